// Round 1
// baseline (912.317 us; speedup 1.0000x reference)
//
#include <hip/hip_runtime.h>
#include <hip/hip_fp16.h>

#define TDIM 2048
#define BDIM 4
#define MROWS 8192   // B*T
#define NDIM 2048
#define KDIM 2048
#define NH 16

typedef __attribute__((ext_vector_type(8))) _Float16 f16x8;
typedef __attribute__((ext_vector_type(4))) _Float16 f16x4;
typedef __attribute__((ext_vector_type(4))) float f32x4;

__device__ __forceinline__ void load16_to_lds(const _Float16* g, _Float16* l) {
  __builtin_amdgcn_global_load_lds((const __attribute__((address_space(1))) void*)g,
                                   (__attribute__((address_space(3))) void*)l,
                                   16, 0, 0);
}

// ---------------- pass 1: fp32 -> fp16 conversion ----------------
__global__ __launch_bounds__(256) void cvt6_kernel(
    const float* __restrict__ s0, const float* __restrict__ s1,
    const float* __restrict__ s2, const float* __restrict__ s3,
    const float* __restrict__ s4, const float* __restrict__ s5,
    _Float16* __restrict__ d0, _Float16* __restrict__ d1,
    _Float16* __restrict__ d2, _Float16* __restrict__ d3,
    _Float16* __restrict__ d4, _Float16* __restrict__ d5) {
  const int z = blockIdx.z;
  const float* s; _Float16* d; int n;
  switch (z) {
    case 0: s = s0; d = d0; n = MROWS * KDIM; break;
    case 1: s = s1; d = d1; n = MROWS * KDIM; break;
    case 2: s = s2; d = d2; n = MROWS * KDIM; break;
    case 3: s = s3; d = d3; n = NDIM * KDIM; break;
    case 4: s = s4; d = d4; n = NDIM * KDIM; break;
    default: s = s5; d = d5; n = NDIM * KDIM; break;
  }
  const int n4 = n >> 2;
  const int stride = gridDim.x * blockDim.x;
  for (int i = blockIdx.x * blockDim.x + threadIdx.x; i < n4; i += stride) {
    float4 f = ((const float4*)s)[i];
    f16x4 h;
    h.x = (_Float16)f.x; h.y = (_Float16)f.y;
    h.z = (_Float16)f.z; h.w = (_Float16)f.w;
    ((f16x4*)d)[i] = h;
  }
}

// ---------------- pass 2: fp16 MFMA GEMM (m97 structure) ----------------
// C[m][n] = sum_k A[m][k] * W[n][k];  z=0: q raw fp16, z=1: k raw fp16,
// z=2: v written fp32 head-split directly into d_out.
__global__ __launch_bounds__(256) void gemm_kernel(
    const _Float16* __restrict__ A0, const _Float16* __restrict__ A1,
    const _Float16* __restrict__ A2,
    const _Float16* __restrict__ W0, const _Float16* __restrict__ W1,
    const _Float16* __restrict__ W2,
    _Float16* __restrict__ qraw, _Float16* __restrict__ kraw,
    float* __restrict__ vout) {
  __shared__ __align__(16) _Float16 As[128 * 32];
  __shared__ __align__(16) _Float16 Bs[128 * 32];

  const int z = blockIdx.z;
  const _Float16* __restrict__ A  = (z == 0) ? A0 : ((z == 1) ? A1 : A2);
  const _Float16* __restrict__ Wt = (z == 0) ? W0 : ((z == 1) ? W1 : W2);

  const int tid  = threadIdx.x;
  const int wave = tid >> 6;
  const int lane = tid & 63;
  const int m0 = blockIdx.y * 128;
  const int n0 = blockIdx.x * 128;

  f32x4 acc[4][4];
  const f32x4 z4 = {0.f, 0.f, 0.f, 0.f};
#pragma unroll
  for (int i = 0; i < 4; ++i)
#pragma unroll
    for (int j = 0; j < 4; ++j) acc[i][j] = z4;

  const int wm = (wave >> 1) * 64;
  const int wn = (wave & 1) * 64;
  const int m_in = lane & 15;
  const int kq = lane >> 4;

  // staging: 512 16B-chunks per 128x32 tile; chunk = i*256 + tid
  const int ch0 = tid,        r0 = ch0 >> 2, c0 = ch0 & 3;
  const int ch1 = 256 + tid,  r1 = ch1 >> 2, c1 = ch1 & 3;
  const size_t gA0 = (size_t)(m0 + r0) * KDIM + c0 * 8;
  const size_t gA1 = (size_t)(m0 + r1) * KDIM + c1 * 8;
  const size_t gB0 = (size_t)(n0 + r0) * KDIM + c0 * 8;
  const size_t gB1 = (size_t)(n0 + r1) * KDIM + c1 * 8;
  _Float16* ldsA0 = &As[(wave * 64) * 8];
  _Float16* ldsA1 = &As[(256 + wave * 64) * 8];
  _Float16* ldsB0 = &Bs[(wave * 64) * 8];
  _Float16* ldsB1 = &Bs[(256 + wave * 64) * 8];

  for (int k0 = 0; k0 < KDIM; k0 += 32) {
    load16_to_lds(A + gA0 + k0, ldsA0);
    load16_to_lds(A + gA1 + k0, ldsA1);
    load16_to_lds(Wt + gB0 + k0, ldsB0);
    load16_to_lds(Wt + gB1 + k0, ldsB1);
    __syncthreads();

    f16x8 a[4], b[4];
#pragma unroll
    for (int mi = 0; mi < 4; ++mi)
      a[mi] = *(const f16x8*)&As[(wm + mi * 16 + m_in) * 32 + kq * 8];
#pragma unroll
    for (int ni = 0; ni < 4; ++ni)
      b[ni] = *(const f16x8*)&Bs[(wn + ni * 16 + m_in) * 32 + kq * 8];
#pragma unroll
    for (int mi = 0; mi < 4; ++mi)
#pragma unroll
      for (int ni = 0; ni < 4; ++ni)
        acc[mi][ni] = __builtin_amdgcn_mfma_f32_16x16x32_f16(a[mi], b[ni], acc[mi][ni], 0, 0, 0);
    __syncthreads();
  }

  // epilogue: C/D layout col=lane&15, row=(lane>>4)*4+reg
  const int rbase = kq * 4;
  if (z < 2) {
    _Float16* __restrict__ raw = (z == 0) ? qraw : kraw;
#pragma unroll
    for (int mi = 0; mi < 4; ++mi) {
      const int m = m0 + wm + mi * 16 + rbase;
#pragma unroll
      for (int ni = 0; ni < 4; ++ni) {
        const int n = n0 + wn + ni * 16 + m_in;
#pragma unroll
        for (int r = 0; r < 4; ++r)
          raw[(size_t)(m + r) * NDIM + n] = (_Float16)acc[mi][ni][r];
      }
    }
  } else {
#pragma unroll
    for (int mi = 0; mi < 4; ++mi) {
      const int mb = m0 + wm + mi * 16 + rbase;
#pragma unroll
      for (int ni = 0; ni < 4; ++ni) {
        const int n = n0 + wn + ni * 16 + m_in;
        const int h = n >> 7, dd = n & 127;
#pragma unroll
        for (int r = 0; r < 4; ++r) {
          const int m = mb + r;
          const int b = m >> 11, t = m & 2047;
          vout[(((size_t)(b * NH + h) * TDIM) + t) * 128 + dd] = acc[mi][ni][r];
        }
      }
    }
  }
}

// ---------------- pass 3: concat + LayerNorm + head-split + RoPE ----------------
// x = [q, c-q]; mu = c/2; var = mean_{2048}((q-c/2)^2)
__global__ __launch_bounds__(256) void ln_rope_kernel(
    const _Float16* __restrict__ qraw, const _Float16* __restrict__ kraw,
    const float* __restrict__ negator,
    const float* __restrict__ q_gamma, const float* __restrict__ q_beta,
    const float* __restrict__ k_gamma, const float* __restrict__ k_beta,
    const int* __restrict__ offset_p,
    float* __restrict__ out) {
  const int row = blockIdx.x;   // b*T + t
  const int mat = blockIdx.y;   // 0: q, 1: k
  const _Float16* __restrict__ raw = mat ? kraw : qraw;
  const float* __restrict__ gamma = mat ? k_gamma : q_gamma;
  const float* __restrict__ beta  = mat ? k_beta  : q_beta;
  float* __restrict__ outb = out + (size_t)mat * ((size_t)BDIM * NH * TDIM * 256);

  const float c = negator[0];
  const float mu = 0.5f * c;
  const int tid = threadIdx.x;

  __shared__ __align__(16) float vals[2048];
  __shared__ float wred[4];

  f16x8 hv = ((const f16x8*)(raw + (size_t)row * 2048))[tid];
  float v[8];
  float ss = 0.f;
#pragma unroll
  for (int j = 0; j < 8; ++j) {
    float x = (float)hv[j] - mu;
    v[j] = x;
    ss += x * x;
  }
  ((float4*)vals)[tid * 2 + 0] = make_float4(v[0], v[1], v[2], v[3]);
  ((float4*)vals)[tid * 2 + 1] = make_float4(v[4], v[5], v[6], v[7]);

#pragma unroll
  for (int o = 32; o > 0; o >>= 1) ss += __shfl_down(ss, o, 64);
  if ((tid & 63) == 0) wred[tid >> 6] = ss;
  __syncthreads();
  const float var = (wred[0] + wred[1] + wred[2] + wred[3]) * (1.0f / 2048.0f);
  const float rstd = rsqrtf(var + 1e-5f);

  const int b = row >> 11, t = row & 2047;
  const float tpos = (float)(t + offset_p[0]);
  const int d = tid;  // within-head channel == tid for every i below

#pragma unroll
  for (int i = 0; i < 16; ++i) {
    const int g = i * 256 + tid;        // LN channel == output channel
    const float sgn = (g < 2048) ? 1.f : -1.f;
    const float y = sgn * vals[g & 2047] * rstd * gamma[g] + beta[g];
    float res;
    if (d < 128) {
      const int gp = g ^ 1;             // partner stays in same half
      const float yp = sgn * vals[gp & 2047] * rstd * gamma[gp] + beta[gp];
      const int p = d >> 1;
      const float invf = exp2f(-(float)p * 0.20762050592854797f); // log2(1e4)/64
      const float th = tpos * invf;
      float sv, cv;
      sincosf(th, &sv, &cv);
      res = (d & 1) ? (y * cv + yp * sv) : (y * cv - yp * sv);
    } else {
      res = y;
    }
    outb[(((size_t)(b * NH + i) * TDIM) + t) * 256 + d] = res;
  }
}

extern "C" void kernel_launch(void* const* d_in, const int* in_sizes, int n_in,
                              void* d_out, int out_size, void* d_ws, size_t ws_size,
                              hipStream_t stream) {
  (void)in_sizes; (void)n_in; (void)out_size; (void)ws_size;
  const float* q_state = (const float*)d_in[0];
  const float* k_state = (const float*)d_in[1];
  const float* v_state = (const float*)d_in[2];
  const float* Wq = (const float*)d_in[3];
  const float* Wk = (const float*)d_in[4];
  const float* Wv = (const float*)d_in[5];
  const float* negator = (const float*)d_in[6];
  const float* q_gamma = (const float*)d_in[7];
  const float* q_beta  = (const float*)d_in[8];
  const float* k_gamma = (const float*)d_in[9];
  const float* k_beta  = (const float*)d_in[10];
  const int* offset    = (const int*)d_in[11];

  float* out = (float*)d_out;
  float* vout = out + (size_t)2 * BDIM * NH * TDIM * 256;  // v region after q,k

  // workspace layout (fp16 elements)
  _Float16* Aq   = (_Float16*)d_ws;
  _Float16* Ak   = Aq + (size_t)MROWS * KDIM;
  _Float16* Av   = Ak + (size_t)MROWS * KDIM;
  _Float16* Wq16 = Av + (size_t)MROWS * KDIM;
  _Float16* Wk16 = Wq16 + (size_t)NDIM * KDIM;
  _Float16* Wv16 = Wk16 + (size_t)NDIM * KDIM;
  _Float16* qraw = Wv16 + (size_t)NDIM * KDIM;
  _Float16* kraw = qraw + (size_t)MROWS * NDIM;
  // total: 3*32MiB + 3*8MiB + 2*32MiB = 184 MiB

  cvt6_kernel<<<dim3(2048, 1, 6), dim3(256), 0, stream>>>(
      q_state, k_state, v_state, Wq, Wk, Wv, Aq, Ak, Av, Wq16, Wk16, Wv16);

  gemm_kernel<<<dim3(16, 64, 3), dim3(256), 0, stream>>>(
      Aq, Ak, Av, Wq16, Wk16, Wv16, qraw, kraw, vout);

  ln_rope_kernel<<<dim3(8192, 2), dim3(256), 0, stream>>>(
      qraw, kraw, negator, q_gamma, q_beta, k_gamma, k_beta, offset, out);
}

// Round 2
// 907.472 us; speedup vs baseline: 1.0053x; 1.0053x over previous
//
#include <hip/hip_runtime.h>
#include <hip/hip_fp16.h>

#define TDIM 2048
#define BDIM 4
#define MROWS 8192   // B*T
#define NDIM 2048
#define KDIM 2048
#define NH 16

typedef __attribute__((ext_vector_type(8))) _Float16 f16x8;
typedef __attribute__((ext_vector_type(4))) _Float16 f16x4;
typedef __attribute__((ext_vector_type(4))) float f32x4;

__device__ __forceinline__ void load16_to_lds(const _Float16* g, _Float16* l) {
  __builtin_amdgcn_global_load_lds((const __attribute__((address_space(1))) void*)g,
                                   (__attribute__((address_space(3))) void*)l,
                                   16, 0, 0);
}

// ---------------- pass 1: fp32 -> fp16 conversion ----------------
__global__ __launch_bounds__(256) void cvt6_kernel(
    const float* __restrict__ s0, const float* __restrict__ s1,
    const float* __restrict__ s2, const float* __restrict__ s3,
    const float* __restrict__ s4, const float* __restrict__ s5,
    _Float16* __restrict__ d0, _Float16* __restrict__ d1,
    _Float16* __restrict__ d2, _Float16* __restrict__ d3,
    _Float16* __restrict__ d4, _Float16* __restrict__ d5) {
  const int z = blockIdx.z;
  const float* s; _Float16* d; int n;
  switch (z) {
    case 0: s = s0; d = d0; n = MROWS * KDIM; break;
    case 1: s = s1; d = d1; n = MROWS * KDIM; break;
    case 2: s = s2; d = d2; n = MROWS * KDIM; break;
    case 3: s = s3; d = d3; n = NDIM * KDIM; break;
    case 4: s = s4; d = d4; n = NDIM * KDIM; break;
    default: s = s5; d = d5; n = NDIM * KDIM; break;
  }
  const int n4 = n >> 2;
  const int stride = gridDim.x * blockDim.x;
  for (int i = blockIdx.x * blockDim.x + threadIdx.x; i < n4; i += stride) {
    float4 f = ((const float4*)s)[i];
    f16x4 h;
    h.x = (_Float16)f.x; h.y = (_Float16)f.y;
    h.z = (_Float16)f.z; h.w = (_Float16)f.w;
    ((f16x4*)d)[i] = h;
  }
}

// ---------------- pass 2: fp16 MFMA GEMM (m97 structure) ----------------
// C[m][n] = sum_k A[m][k] * W[n][k];  z=0: q raw fp16, z=1: k raw fp16,
// z=2: v written fp32 head-split directly into d_out.
__global__ __launch_bounds__(256) void gemm_kernel(
    const _Float16* __restrict__ A0, const _Float16* __restrict__ A1,
    const _Float16* __restrict__ A2,
    const _Float16* __restrict__ W0, const _Float16* __restrict__ W1,
    const _Float16* __restrict__ W2,
    _Float16* __restrict__ qraw, _Float16* __restrict__ kraw,
    float* __restrict__ vout) {
  __shared__ __align__(16) _Float16 As[128 * 32];
  __shared__ __align__(16) _Float16 Bs[128 * 32];

  const int z = blockIdx.z;
  const _Float16* __restrict__ A  = (z == 0) ? A0 : ((z == 1) ? A1 : A2);
  const _Float16* __restrict__ Wt = (z == 0) ? W0 : ((z == 1) ? W1 : W2);

  const int tid  = threadIdx.x;
  const int wave = tid >> 6;
  const int lane = tid & 63;
  const int m0 = blockIdx.y * 128;
  const int n0 = blockIdx.x * 128;

  f32x4 acc[4][4];
  const f32x4 z4 = {0.f, 0.f, 0.f, 0.f};
#pragma unroll
  for (int i = 0; i < 4; ++i)
#pragma unroll
    for (int j = 0; j < 4; ++j) acc[i][j] = z4;

  const int wm = (wave >> 1) * 64;
  const int wn = (wave & 1) * 64;
  const int m_in = lane & 15;
  const int kq = lane >> 4;

  // staging: 512 16B-chunks per 128x32 tile; chunk = i*256 + tid
  const int ch0 = tid,        r0 = ch0 >> 2, c0 = ch0 & 3;
  const int ch1 = 256 + tid,  r1 = ch1 >> 2, c1 = ch1 & 3;
  const size_t gA0 = (size_t)(m0 + r0) * KDIM + c0 * 8;
  const size_t gA1 = (size_t)(m0 + r1) * KDIM + c1 * 8;
  const size_t gB0 = (size_t)(n0 + r0) * KDIM + c0 * 8;
  const size_t gB1 = (size_t)(n0 + r1) * KDIM + c1 * 8;
  _Float16* ldsA0 = &As[(wave * 64) * 8];
  _Float16* ldsA1 = &As[(256 + wave * 64) * 8];
  _Float16* ldsB0 = &Bs[(wave * 64) * 8];
  _Float16* ldsB1 = &Bs[(256 + wave * 64) * 8];

  for (int k0 = 0; k0 < KDIM; k0 += 32) {
    load16_to_lds(A + gA0 + k0, ldsA0);
    load16_to_lds(A + gA1 + k0, ldsA1);
    load16_to_lds(Wt + gB0 + k0, ldsB0);
    load16_to_lds(Wt + gB1 + k0, ldsB1);
    __syncthreads();

    f16x8 a[4], b[4];
#pragma unroll
    for (int mi = 0; mi < 4; ++mi)
      a[mi] = *(const f16x8*)&As[(wm + mi * 16 + m_in) * 32 + kq * 8];
#pragma unroll
    for (int ni = 0; ni < 4; ++ni)
      b[ni] = *(const f16x8*)&Bs[(wn + ni * 16 + m_in) * 32 + kq * 8];
#pragma unroll
    for (int mi = 0; mi < 4; ++mi)
#pragma unroll
      for (int ni = 0; ni < 4; ++ni)
        acc[mi][ni] = __builtin_amdgcn_mfma_f32_16x16x32_f16(a[mi], b[ni], acc[mi][ni], 0, 0, 0);
    __syncthreads();
  }

  // epilogue: C/D layout col=lane&15, row=(lane>>4)*4+reg
  const int rbase = kq * 4;
  if (z < 2) {
    _Float16* __restrict__ raw = (z == 0) ? qraw : kraw;
#pragma unroll
    for (int mi = 0; mi < 4; ++mi) {
      const int m = m0 + wm + mi * 16 + rbase;
#pragma unroll
      for (int ni = 0; ni < 4; ++ni) {
        const int n = n0 + wn + ni * 16 + m_in;
#pragma unroll
        for (int r = 0; r < 4; ++r)
          raw[(size_t)(m + r) * NDIM + n] = (_Float16)acc[mi][ni][r];
      }
    }
  } else {
#pragma unroll
    for (int mi = 0; mi < 4; ++mi) {
      const int mb = m0 + wm + mi * 16 + rbase;
#pragma unroll
      for (int ni = 0; ni < 4; ++ni) {
        const int n = n0 + wn + ni * 16 + m_in;
        const int h = n >> 7, dd = n & 127;
#pragma unroll
        for (int r = 0; r < 4; ++r) {
          const int m = mb + r;
          const int b = m >> 11, t = m & 2047;
          vout[(((size_t)(b * NH + h) * TDIM) + t) * 128 + dd] = acc[mi][ni][r];
        }
      }
    }
  }
}

// ---------------- pass 3: concat + LayerNorm + head-split + RoPE ----------------
// x = [q, c-q]; mu = c/2; var = mean_{2048}((q-c/2)^2)
// RoPE angle th = tpos * 10000^{-(d>>1)/64} depends only on (t, d) -> hoisted
// out of the 16-head loop (was 33.5M sincosf calls, now 2M).
__global__ __launch_bounds__(256) void ln_rope_kernel(
    const _Float16* __restrict__ qraw, const _Float16* __restrict__ kraw,
    const float* __restrict__ negator,
    const float* __restrict__ q_gamma, const float* __restrict__ q_beta,
    const float* __restrict__ k_gamma, const float* __restrict__ k_beta,
    const int* __restrict__ offset_p,
    float* __restrict__ out) {
  const int row = blockIdx.x;   // b*T + t
  const int mat = blockIdx.y;   // 0: q, 1: k
  const _Float16* __restrict__ raw = mat ? kraw : qraw;
  const float* __restrict__ gamma = mat ? k_gamma : q_gamma;
  const float* __restrict__ beta  = mat ? k_beta  : q_beta;
  float* __restrict__ outb = out + (size_t)mat * ((size_t)BDIM * NH * TDIM * 256);

  const float c = negator[0];
  const float mu = 0.5f * c;
  const int tid = threadIdx.x;

  __shared__ __align__(16) float vals[2048];
  __shared__ float wred[4];

  const int b = row >> 11, t = row & 2047;
  const float tpos = (float)(t + offset_p[0]);
  const int d = tid;  // within-head channel == tid for every head below

  // RoPE cos/sin — loop-invariant across heads; compute ONCE per lane.
  // Latency hides under the LN reduction + __syncthreads below.
  float sv = 0.f, cv = 0.f;
  if (d < 128) {
    const int p = d >> 1;
    const float invf = exp2f(-(float)p * 0.20762050592854797f); // log2(1e4)/64
    sincosf(tpos * invf, &sv, &cv);
  }

  f16x8 hv = ((const f16x8*)(raw + (size_t)row * 2048))[tid];
  float v[8];
  float ss = 0.f;
#pragma unroll
  for (int j = 0; j < 8; ++j) {
    float x = (float)hv[j] - mu;
    v[j] = x;
    ss += x * x;
  }
  ((float4*)vals)[tid * 2 + 0] = make_float4(v[0], v[1], v[2], v[3]);
  ((float4*)vals)[tid * 2 + 1] = make_float4(v[4], v[5], v[6], v[7]);

#pragma unroll
  for (int o = 32; o > 0; o >>= 1) ss += __shfl_down(ss, o, 64);
  if ((tid & 63) == 0) wred[tid >> 6] = ss;
  __syncthreads();
  const float var = (wred[0] + wred[1] + wred[2] + wred[3]) * (1.0f / 2048.0f);
  const float rstd = rsqrtf(var + 1e-5f);

#pragma unroll
  for (int i = 0; i < 16; ++i) {
    const int g = i * 256 + tid;        // LN channel == output channel
    const float sgn = (g < 2048) ? 1.f : -1.f;
    const float y = sgn * vals[g & 2047] * rstd * gamma[g] + beta[g];
    float res;
    if (d < 128) {
      const int gp = g ^ 1;             // partner stays in same half
      const float yp = sgn * vals[gp & 2047] * rstd * gamma[gp] + beta[gp];
      res = (d & 1) ? (y * cv + yp * sv) : (y * cv - yp * sv);
    } else {
      res = y;
    }
    outb[(((size_t)(b * NH + i) * TDIM) + t) * 256 + d] = res;
  }
}

extern "C" void kernel_launch(void* const* d_in, const int* in_sizes, int n_in,
                              void* d_out, int out_size, void* d_ws, size_t ws_size,
                              hipStream_t stream) {
  (void)in_sizes; (void)n_in; (void)out_size; (void)ws_size;
  const float* q_state = (const float*)d_in[0];
  const float* k_state = (const float*)d_in[1];
  const float* v_state = (const float*)d_in[2];
  const float* Wq = (const float*)d_in[3];
  const float* Wk = (const float*)d_in[4];
  const float* Wv = (const float*)d_in[5];
  const float* negator = (const float*)d_in[6];
  const float* q_gamma = (const float*)d_in[7];
  const float* q_beta  = (const float*)d_in[8];
  const float* k_gamma = (const float*)d_in[9];
  const float* k_beta  = (const float*)d_in[10];
  const int* offset    = (const int*)d_in[11];

  float* out = (float*)d_out;
  float* vout = out + (size_t)2 * BDIM * NH * TDIM * 256;  // v region after q,k

  // workspace layout (fp16 elements)
  _Float16* Aq   = (_Float16*)d_ws;
  _Float16* Ak   = Aq + (size_t)MROWS * KDIM;
  _Float16* Av   = Ak + (size_t)MROWS * KDIM;
  _Float16* Wq16 = Av + (size_t)MROWS * KDIM;
  _Float16* Wk16 = Wq16 + (size_t)NDIM * KDIM;
  _Float16* Wv16 = Wk16 + (size_t)NDIM * KDIM;
  _Float16* qraw = Wv16 + (size_t)NDIM * KDIM;
  _Float16* kraw = qraw + (size_t)MROWS * NDIM;
  // total: 3*32MiB + 3*8MiB + 2*32MiB = 184 MiB

  cvt6_kernel<<<dim3(2048, 1, 6), dim3(256), 0, stream>>>(
      q_state, k_state, v_state, Wq, Wk, Wv, Aq, Ak, Av, Wq16, Wk16, Wv16);

  gemm_kernel<<<dim3(16, 64, 3), dim3(256), 0, stream>>>(
      Aq, Ak, Av, Wq16, Wk16, Wv16, qraw, kraw, vout);

  ln_rope_kernel<<<dim3(8192, 2), dim3(256), 0, stream>>>(
      qraw, kraw, negator, q_gamma, q_beta, k_gamma, k_beta, offset, out);
}